// Round 1
// baseline (168.894 us; speedup 1.0000x reference)
//
#include <hip/hip_runtime.h>

#define BATCH 512
#define DIM   256
#define UNITS 256

typedef __bf16 bf16x8 __attribute__((ext_vector_type(8)));
typedef float  f32x4  __attribute__((ext_vector_type(4)));
typedef unsigned short us8 __attribute__((ext_vector_type(8)));

__device__ __forceinline__ unsigned short f2bf(float f) {
    unsigned int x = __builtin_bit_cast(unsigned int, f);
    x += 0x7FFFu + ((x >> 16) & 1u);      // round-to-nearest-even
    return (unsigned short)(x >> 16);
}

__device__ __forceinline__ bf16x8 ld_bf8(const unsigned short* p) {
    uint4 u = *reinterpret_cast<const uint4*>(p);
    return __builtin_bit_cast(bf16x8, u);
}

__device__ __forceinline__ bf16x8 cvt8(float4 a, float4 b) {
    us8 t;
    t[0] = f2bf(a.x); t[1] = f2bf(a.y); t[2] = f2bf(a.z); t[3] = f2bf(a.w);
    t[4] = f2bf(b.x); t[5] = f2bf(b.y); t[6] = f2bf(b.z); t[7] = f2bf(b.w);
    return __builtin_bit_cast(bf16x8, t);
}

// Prep: mu_out (f32), s_b = x.x + tr(Sigma_b), softplus table, W^T -> bf16
__global__ __launch_bounds__(256) void prep_kernel(
    const float* __restrict__ mu_in, const float* __restrict__ Sigma,
    const float* __restrict__ W, const float* __restrict__ w_sigma,
    float* __restrict__ mu_out, unsigned short* __restrict__ Wt,
    float* __restrict__ sb, float* __restrict__ sp)
{
    const int b = blockIdx.x;
    const int t = threadIdx.x;

    __shared__ float mrow[DIM];
    mrow[t] = mu_in[b * DIM + t];
    __syncthreads();

    float acc = 0.f;
#pragma unroll 8
    for (int d = 0; d < DIM; ++d) acc += mrow[d] * W[d * UNITS + t];
    mu_out[b * UNITS + t] = acc;

    // s_b = sum(mu^2) + trace(Sigma_b)
    float xv  = mrow[t];
    float val = xv * xv + Sigma[(size_t)b * DIM * DIM + (size_t)t * (DIM + 1)];
#pragma unroll
    for (int o = 32; o > 0; o >>= 1) val += __shfl_down(val, o);
    __shared__ float wsum[4];
    if ((t & 63) == 0) wsum[t >> 6] = val;
    __syncthreads();
    if (t == 0) sb[b] = wsum[0] + wsum[1] + wsum[2] + wsum[3];

    if (b < UNITS) Wt[b * DIM + t] = f2bf(W[t * UNITS + b]);   // Wt[u][d] = W[d][u]
    if (b == 0)    sp[t] = log1pf(expf(w_sigma[t]));
}

// Main: per-block batch b. Strips of 128 v-columns.
// Stage1: P = Sigma_b @ W    (A = Sigma rows f32->bf16 from global, B from Wt)
// Stage2: out = W^T @ P      (A from Wt, B from P^T in LDS)
__global__ __launch_bounds__(512) void sigma_kernel(
    const float* __restrict__ Sigma, const unsigned short* __restrict__ Wt,
    const float* __restrict__ sb, const float* __restrict__ sp,
    float* __restrict__ out)
{
    __shared__ unsigned short Pt[128][264];   // P^T, padded: 264*2B=528B ≡ 4 mod 32 dwords

    const int b    = blockIdx.x;
    const int tid  = threadIdx.x;
    const int lane = tid & 63;
    const int w    = tid >> 6;     // 0..7
    const int wr   = w >> 1;       // 0..3  (64-row block: d in stage1, u in stage2)
    const int wc   = w & 1;        // 0..1  (64-col block within 128 strip)
    const int lq   = lane >> 4;    // 0..3
    const int lr   = lane & 15;    // 0..15
    const int m0   = wr * 64;
    const int n0   = wc * 64;

    const float* S = Sigma + (size_t)b * DIM * DIM;
    float*       O = out   + (size_t)b * UNITS * UNITS;
    const float  sbv = sb[b];

    for (int vt = 0; vt < 2; ++vt) {
        const int v0 = vt * 128;

        f32x4 acc[4][4];
#pragma unroll
        for (int i = 0; i < 4; ++i)
#pragma unroll
            for (int j = 0; j < 4; ++j)
#pragma unroll
                for (int r = 0; r < 4; ++r) acc[i][j][r] = 0.f;

        // ---- Stage 1: P[d][v] = sum_e Sigma[d][e] * W[e][v], K over e ----
        for (int kk = 0; kk < 8; ++kk) {
            const int k0 = kk * 32;
            bf16x8 af[4], bfr[4];
#pragma unroll
            for (int i = 0; i < 4; ++i) {
                const float4* p = reinterpret_cast<const float4*>(
                    S + (size_t)(m0 + 16 * i + lr) * DIM + k0 + 8 * lq);
                af[i] = cvt8(p[0], p[1]);
            }
#pragma unroll
            for (int j = 0; j < 4; ++j)
                bfr[j] = ld_bf8(Wt + (size_t)(v0 + n0 + 16 * j + lr) * DIM + k0 + 8 * lq);
#pragma unroll
            for (int i = 0; i < 4; ++i)
#pragma unroll
                for (int j = 0; j < 4; ++j)
                    acc[i][j] = __builtin_amdgcn_mfma_f32_16x16x32_bf16(
                        af[i], bfr[j], acc[i][j], 0, 0, 0);
        }

        // write P^T into LDS: D row = d (m), col = v (n); 4 regs = 4 consecutive d
#pragma unroll
        for (int i = 0; i < 4; ++i) {
#pragma unroll
            for (int j = 0; j < 4; ++j) {
                const int d0 = m0 + 16 * i + 4 * lq;
                const int vl = n0 + 16 * j + lr;
                uint2 pk;
                pk.x = (unsigned)f2bf(acc[i][j][0]) | ((unsigned)f2bf(acc[i][j][1]) << 16);
                pk.y = (unsigned)f2bf(acc[i][j][2]) | ((unsigned)f2bf(acc[i][j][3]) << 16);
                *reinterpret_cast<uint2*>(&Pt[vl][d0]) = pk;
            }
        }
        __syncthreads();

        // ---- Stage 2: out[u][v] = sum_d W[d][u] * P[d][v], K over d ----
#pragma unroll
        for (int i = 0; i < 4; ++i)
#pragma unroll
            for (int j = 0; j < 4; ++j)
#pragma unroll
                for (int r = 0; r < 4; ++r) acc[i][j][r] = 0.f;

        for (int kk = 0; kk < 8; ++kk) {
            const int k0 = kk * 32;
            bf16x8 af[4], bfr[4];
#pragma unroll
            for (int i = 0; i < 4; ++i)
                af[i] = ld_bf8(Wt + (size_t)(m0 + 16 * i + lr) * DIM + k0 + 8 * lq);
#pragma unroll
            for (int j = 0; j < 4; ++j)
                bfr[j] = ld_bf8(&Pt[n0 + 16 * j + lr][k0 + 8 * lq]);
#pragma unroll
            for (int i = 0; i < 4; ++i)
#pragma unroll
                for (int j = 0; j < 4; ++j)
                    acc[i][j] = __builtin_amdgcn_mfma_f32_16x16x32_bf16(
                        af[i], bfr[j], acc[i][j], 0, 0, 0);
        }

        // ---- Epilogue: diag add, finite cleanup, abs-diag, store ----
#pragma unroll
        for (int i = 0; i < 4; ++i) {
#pragma unroll
            for (int j = 0; j < 4; ++j) {
                const int   vg  = v0 + n0 + 16 * j + lr;
                const float spv = sp[vg];
#pragma unroll
                for (int r = 0; r < 4; ++r) {
                    const int u = m0 + 16 * i + 4 * lq + r;
                    float val = acc[i][j][r];
                    if (u == vg) val += sbv * spv;
                    val = __builtin_isfinite(val) ? val : 0.0f;
                    if (u == vg) val = fabsf(val);
                    O[(size_t)u * UNITS + vg] = val;
                }
            }
        }
        __syncthreads();
    }
}

extern "C" void kernel_launch(void* const* d_in, const int* in_sizes, int n_in,
                              void* d_out, int out_size, void* d_ws, size_t ws_size,
                              hipStream_t stream) {
    const float* mu_in  = (const float*)d_in[0];
    const float* Sigma  = (const float*)d_in[1];
    const float* w_mu   = (const float*)d_in[2];
    const float* w_sig  = (const float*)d_in[3];

    float* mu_out  = (float*)d_out;
    float* Sig_out = (float*)d_out + BATCH * UNITS;

    unsigned short* Wt = (unsigned short*)d_ws;                       // 131072 B
    float* sb = (float*)((char*)d_ws + (size_t)DIM * UNITS * 2);      // 512 f32
    float* sp = sb + BATCH;                                           // 256 f32

    prep_kernel<<<BATCH, 256, 0, stream>>>(mu_in, Sigma, w_mu, w_sig, mu_out, Wt, sb, sp);
    sigma_kernel<<<BATCH, 512, 0, stream>>>(Sigma, Wt, sb, sp, Sig_out);
}

// Round 2
// 162.062 us; speedup vs baseline: 1.0422x; 1.0422x over previous
//
#include <hip/hip_runtime.h>

#define BATCH 512
#define DIM   256
#define UNITS 256

typedef __bf16 bf16x8 __attribute__((ext_vector_type(8)));
typedef float  f32x4  __attribute__((ext_vector_type(4)));

__device__ __forceinline__ bf16x8 ld_bf8(const unsigned short* p) {
    uint4 u = *reinterpret_cast<const uint4*>(p);
    return __builtin_bit_cast(bf16x8, u);
}

__device__ __forceinline__ bf16x8 cvt8(float4 a, float4 b) {
    bf16x8 r;
    r[0] = (__bf16)a.x; r[1] = (__bf16)a.y; r[2] = (__bf16)a.z; r[3] = (__bf16)a.w;
    r[4] = (__bf16)b.x; r[5] = (__bf16)b.y; r[6] = (__bf16)b.z; r[7] = (__bf16)b.w;
    return r;
}

// Prep: mu_out (f32), s_b = x.x + tr(Sigma_b), softplus table, W^T -> bf16
__global__ __launch_bounds__(256) void prep_kernel(
    const float* __restrict__ mu_in, const float* __restrict__ Sigma,
    const float* __restrict__ W, const float* __restrict__ w_sigma,
    float* __restrict__ mu_out, unsigned short* __restrict__ Wt,
    float* __restrict__ sb, float* __restrict__ sp)
{
    const int b = blockIdx.x;
    const int t = threadIdx.x;

    __shared__ float mrow[DIM];
    mrow[t] = mu_in[b * DIM + t];
    __syncthreads();

    float acc = 0.f;
#pragma unroll 8
    for (int d = 0; d < DIM; ++d) acc += mrow[d] * W[d * UNITS + t];
    mu_out[b * UNITS + t] = acc;

    // s_b = sum(mu^2) + trace(Sigma_b)
    float xv  = mrow[t];
    float val = xv * xv + Sigma[(size_t)b * DIM * DIM + (size_t)t * (DIM + 1)];
#pragma unroll
    for (int o = 32; o > 0; o >>= 1) val += __shfl_down(val, o);
    __shared__ float wsum[4];
    if ((t & 63) == 0) wsum[t >> 6] = val;
    __syncthreads();
    if (t == 0) sb[b] = wsum[0] + wsum[1] + wsum[2] + wsum[3];

    if (b < UNITS) Wt[b * DIM + t] = __builtin_bit_cast(unsigned short, (__bf16)W[t * UNITS + b]);
    if (b == 0)    sp[t] = log1pf(expf(w_sigma[t]));
}

// Main: one block per (batch b, 64-col v-strip s). 256 threads = 4 waves.
// Stage1: P[d][v] = Sigma_b @ W   (A = Sigma rows f32->bf16, B = Wt from L2)
// Stage2: out[u][v] = W^T @ P     (A = Wt, B = P^T from LDS)
__global__ __launch_bounds__(256, 4) void sigma_kernel(
    const float* __restrict__ Sigma, const unsigned short* __restrict__ Wt,
    const float* __restrict__ sb, const float* __restrict__ sp,
    float* __restrict__ out)
{
    __shared__ unsigned short Pt[64][264];   // P^T strip: [v][d], padded row = 528 B

    // XCD-chunked swizzle: consecutive logical blocks (same batch's strips)
    // land on the same XCD. 2048 % 8 == 0 -> bijective.
    const int bid     = blockIdx.x;
    const int logical = (bid & 7) * (2048 / 8) + (bid >> 3);
    const int b       = logical >> 2;
    const int s       = logical & 3;
    const int v0      = s * 64;

    const int tid  = threadIdx.x;
    const int lane = tid & 63;
    const int w    = tid >> 6;     // 0..3 -> owns 64 d-rows (stage1) / u-rows (stage2)
    const int lq   = lane >> 4;    // 0..3
    const int lr   = lane & 15;    // 0..15
    const int m0   = w * 64;

    const float* S = Sigma + (size_t)b * DIM * DIM;
    float*       O = out   + (size_t)b * UNITS * UNITS;
    const float  sbv = sb[b];

    f32x4 acc[4][4];
#pragma unroll
    for (int i = 0; i < 4; ++i)
#pragma unroll
        for (int j = 0; j < 4; ++j)
#pragma unroll
            for (int r = 0; r < 4; ++r) acc[i][j][r] = 0.f;

    // ---- Stage 1: P[d][v] = sum_e Sigma[d][e] * W[e][v] ----
    for (int kk = 0; kk < 8; ++kk) {
        const int k0 = kk * 32;
        bf16x8 af[4], bfr[4];
#pragma unroll
        for (int i = 0; i < 4; ++i) {
            const float4* p = reinterpret_cast<const float4*>(
                S + (size_t)(m0 + 16 * i + lr) * DIM + k0 + 8 * lq);
            af[i] = cvt8(p[0], p[1]);
        }
#pragma unroll
        for (int j = 0; j < 4; ++j)
            bfr[j] = ld_bf8(Wt + (size_t)(v0 + 16 * j + lr) * DIM + k0 + 8 * lq);
#pragma unroll
        for (int i = 0; i < 4; ++i)
#pragma unroll
            for (int j = 0; j < 4; ++j)
                acc[i][j] = __builtin_amdgcn_mfma_f32_16x16x32_bf16(
                    af[i], bfr[j], acc[i][j], 0, 0, 0);
    }

    // write P^T into LDS: row v, cols d; 4 C-regs = 4 consecutive d -> packed 8 B
#pragma unroll
    for (int i = 0; i < 4; ++i) {
#pragma unroll
        for (int j = 0; j < 4; ++j) {
            const int d0 = m0 + 16 * i + 4 * lq;
            const int vl = 16 * j + lr;
            uint2 pk;
            unsigned short h0 = __builtin_bit_cast(unsigned short, (__bf16)acc[i][j][0]);
            unsigned short h1 = __builtin_bit_cast(unsigned short, (__bf16)acc[i][j][1]);
            unsigned short h2 = __builtin_bit_cast(unsigned short, (__bf16)acc[i][j][2]);
            unsigned short h3 = __builtin_bit_cast(unsigned short, (__bf16)acc[i][j][3]);
            pk.x = (unsigned)h0 | ((unsigned)h1 << 16);
            pk.y = (unsigned)h2 | ((unsigned)h3 << 16);
            *reinterpret_cast<uint2*>(&Pt[vl][d0]) = pk;
        }
    }
    __syncthreads();

    // ---- Stage 2: out[u][v] = sum_d W[d][u] * P[d][v] ----
#pragma unroll
    for (int i = 0; i < 4; ++i)
#pragma unroll
        for (int j = 0; j < 4; ++j)
#pragma unroll
            for (int r = 0; r < 4; ++r) acc[i][j][r] = 0.f;

    for (int kk = 0; kk < 8; ++kk) {
        const int k0 = kk * 32;
        bf16x8 af[4], bfr[4];
#pragma unroll
        for (int i = 0; i < 4; ++i)
            af[i] = ld_bf8(Wt + (size_t)(m0 + 16 * i + lr) * DIM + k0 + 8 * lq);
#pragma unroll
        for (int j = 0; j < 4; ++j)
            bfr[j] = ld_bf8(&Pt[16 * j + lr][k0 + 8 * lq]);
#pragma unroll
        for (int i = 0; i < 4; ++i)
#pragma unroll
            for (int j = 0; j < 4; ++j)
                acc[i][j] = __builtin_amdgcn_mfma_f32_16x16x32_bf16(
                    af[i], bfr[j], acc[i][j], 0, 0, 0);
    }

    // ---- Epilogue: diag add, finite cleanup, abs-diag, store ----
#pragma unroll
    for (int i = 0; i < 4; ++i) {
#pragma unroll
        for (int j = 0; j < 4; ++j) {
            const int   vg  = v0 + 16 * j + lr;
            const float spv = sp[vg];
#pragma unroll
            for (int r = 0; r < 4; ++r) {
                const int u = m0 + 16 * i + 4 * lq + r;
                float val = acc[i][j][r];
                if (u == vg) val += sbv * spv;
                val = __builtin_isfinite(val) ? val : 0.0f;
                if (u == vg) val = fabsf(val);
                O[(size_t)u * UNITS + vg] = val;
            }
        }
    }
}

extern "C" void kernel_launch(void* const* d_in, const int* in_sizes, int n_in,
                              void* d_out, int out_size, void* d_ws, size_t ws_size,
                              hipStream_t stream) {
    const float* mu_in  = (const float*)d_in[0];
    const float* Sigma  = (const float*)d_in[1];
    const float* w_mu   = (const float*)d_in[2];
    const float* w_sig  = (const float*)d_in[3];

    float* mu_out  = (float*)d_out;
    float* Sig_out = (float*)d_out + BATCH * UNITS;

    unsigned short* Wt = (unsigned short*)d_ws;                       // 131072 B
    float* sb = (float*)((char*)d_ws + (size_t)DIM * UNITS * 2);      // 512 f32
    float* sp = sb + BATCH;                                           // 256 f32

    prep_kernel<<<BATCH, 256, 0, stream>>>(mu_in, Sigma, w_mu, w_sig, mu_out, Wt, sb, sp);
    sigma_kernel<<<BATCH * 4, 256, 0, stream>>>(Sigma, Wt, sb, sp, Sig_out);
}